// Round 6
// baseline (631.630 us; speedup 1.0000x reference)
//
#include <hip/hip_runtime.h>
#include <hip/hip_bf16.h>
#include <stdint.h>
#include <type_traits>

// ---------------------------------------------------------------------------
// GCN on MI355X: 3x (dense GEMM -> spmm -> bias [-> relu -> concat])
// fp16 activations/weights, fp32 accumulation everywhere.
// R6: spmm slice chosen by ACTUAL XCD id (s_getreg XCC_ID) + per-slice atomic
//     row counters (guaranteed 2.5MB/XCD L2-resident gathers, dispatch-map
//     independent); parallel 1024-thr prefix scan; LDS-tiled transposes.
// ---------------------------------------------------------------------------

typedef _Float16 half8 __attribute__((ext_vector_type(8)));
typedef _Float16 half4 __attribute__((ext_vector_type(4)));
typedef float    f32x4 __attribute__((ext_vector_type(4)));

#define N_NODES 10000
#define M_PAD   10112   // 158 * 64
#define N_EDGES 320000

__device__ __forceinline__ void async16(const void* g, void* l) {
    __builtin_amdgcn_global_load_lds(
        (const __attribute__((address_space(1))) void*)g,
        (__attribute__((address_space(3))) void*)l, 16, 0, 0);
}

// hwreg(HW_REG_XCC_ID=20, offset=0, size=32) -> imm = 20 | (31<<11)
__device__ __forceinline__ uint32_t xcc_id() {
    return __builtin_amdgcn_s_getreg(20 | (31 << 11)) & 7;
}

// ---------------------------------------------------------------------------
// prep (block-segmented): x fp32->fp16 (5000 blks), LDS-tiled W transposes
// (256+512+256 blks), zero counts+work (40 blks).
// ---------------------------------------------------------------------------
#define PREP_XB   5000
#define PREP_W0B  256    // 512x512  : 16x16 tiles of 32x32
#define PREP_W1B  512    // 1024x512 : 32x16
#define PREP_W2B  256    // 1024x256 : 32x8
#define PREP_ZB   40
#define PREP_BLKS (PREP_XB + PREP_W0B + PREP_W1B + PREP_W2B + PREP_ZB)

__device__ __forceinline__ void tile_tr(const float* __restrict__ W,
                                        _Float16* __restrict__ Wt,
                                        int K, int Nc, int tR, int tC, int t) {
    __shared__ float tile[32][33];
    const int ty = t >> 5, tx = t & 31;
#pragma unroll
    for (int it = 0; it < 4; ++it)
        tile[ty + 8 * it][tx] = W[(size_t)(tR * 32 + ty + 8 * it) * Nc + tC * 32 + tx];
    __syncthreads();
#pragma unroll
    for (int it = 0; it < 4; ++it)
        Wt[(size_t)(tC * 32 + ty + 8 * it) * K + tR * 32 + tx] =
            (_Float16)tile[tx][ty + 8 * it];
}

__global__ __launch_bounds__(256) void prep(
    const float* __restrict__ x,  _Float16* __restrict__ Xh,
    const float* __restrict__ W0, _Float16* __restrict__ W0t,
    const float* __restrict__ W1, _Float16* __restrict__ W1t,
    const float* __restrict__ W2, _Float16* __restrict__ W2t,
    int* __restrict__ counts, int* __restrict__ work) {
    const int t = threadIdx.x;
    int b = blockIdx.x;
    if (b < PREP_XB) {
        int i = b * 256 + t;                 // exactly 10000*512/4 threads
        f32x4 v = *(const f32x4*)(x + (size_t)i * 4);
        half4 h;
        h[0] = (_Float16)v[0]; h[1] = (_Float16)v[1];
        h[2] = (_Float16)v[2]; h[3] = (_Float16)v[3];
        *(half4*)(Xh + (size_t)i * 4) = h;
        return;
    }
    b -= PREP_XB;
    if (b < PREP_W0B) { tile_tr(W0, W0t, 512, 512, b >> 4, b & 15, t); return; }
    b -= PREP_W0B;
    if (b < PREP_W1B) { tile_tr(W1, W1t, 1024, 512, b >> 4, b & 15, t); return; }
    b -= PREP_W1B;
    if (b < PREP_W2B) { tile_tr(W2, W2t, 1024, 256, b >> 3, b & 7, t); return; }
    b -= PREP_W2B;
    {
        int i = b * 256 + t;
        if (i < N_NODES) counts[i] = 0;
        else if (i < N_NODES + 16) work[i - N_NODES] = 0;
    }
}

// ---------------------------------------------------------------------------
// CSR build
// ---------------------------------------------------------------------------
__global__ void hist_rows(const int* __restrict__ rows, int* __restrict__ counts, int E) {
    int i = blockIdx.x * blockDim.x + threadIdx.x;
    if (i < E) atomicAdd(&counts[rows[i]], 1);
}

// one block, 1024 threads: exclusive scan of counts -> row_ptr, cursor
__global__ __launch_bounds__(1024) void scan_rowptr(
    const int* __restrict__ counts,
    int* __restrict__ row_ptr,
    int* __restrict__ cursor) {
    const int t = threadIdx.x, lane = t & 63, wid = t >> 6;
    const int base = t * 10;
    int c[10];
    int s = 0;
    if (base < N_NODES) {
#pragma unroll
        for (int j = 0; j < 10; ++j) { s += counts[base + j]; c[j] = s; }  // inclusive
    }
    // wave inclusive scan of s
    int v = s;
#pragma unroll
    for (int d = 1; d < 64; d <<= 1) {
        int u = __shfl_up(v, d, 64);
        if (lane >= d) v += u;
    }
    __shared__ int wsum[16];
    if (lane == 63) wsum[wid] = v;
    __syncthreads();
    if (t == 0) {
        int run = 0;
#pragma unroll
        for (int i = 0; i < 16; ++i) { int x = wsum[i]; wsum[i] = run; run += x; }
    }
    __syncthreads();
    if (base < N_NODES) {
        const int excl = wsum[wid] + v - s;      // exclusive prefix at base
        row_ptr[base] = excl; cursor[base] = excl;
#pragma unroll
        for (int j = 1; j < 10; ++j) {
            int val = excl + c[j - 1];
            row_ptr[base + j] = val; cursor[base + j] = val;
        }
    }
    if (t == 0) row_ptr[N_NODES] = N_EDGES;
}

// packed edge record: {col as int bits, val}
__global__ void scatter_edges(const int* __restrict__ rows,
                              const int* __restrict__ cols,
                              const float* __restrict__ vals,
                              int* __restrict__ cursor,
                              float2* __restrict__ ev, int E) {
    int i = blockIdx.x * blockDim.x + threadIdx.x;
    if (i < E) {
        int r = rows[i];
        int p = atomicAdd(&cursor[r], 1);
        ev[p] = make_float2(__int_as_float(cols[i]), vals[i]);
    }
}

// ---------------------------------------------------------------------------
// GEMM: C[M_PAD x Nc] = A[M_PAD x K] * Bt[Nc x K]^T. fp16 in/out, fp32 acc.
// Tile TM x TN, BK=32, 4 waves in 2x2, double-buffered LDS, global_load_lds
// width=16 staging. TM=64 -> 632 blocks (2.5/CU).
// ---------------------------------------------------------------------------
template <int TM, int TN>
__global__ __launch_bounds__(256) void gemm_f16_t(
    const _Float16* __restrict__ A,
    const _Float16* __restrict__ Bt,
    _Float16* __restrict__ C,
    int K, int Nc)
{
    constexpr int WM = TM / 2;
    constexpr int WN = TN / 2;
    constexpr int MT = WM / 16;
    constexpr int NT = WN / 16;
    constexpr int NCHUNK = (TM + TN) / 16;
    constexpr int CA = TM / 16;

    __shared__ _Float16 As[2][TM * 32];
    __shared__ _Float16 Bs[2][TN * 32];

    const int t    = threadIdx.x;
    const int lane = t & 63;
    const int wid  = t >> 6;
    const int wrow = wid >> 1;
    const int wcol = wid & 1;
    const int quad = lane >> 4;
    const int l15  = lane & 15;

    const int rowBase = blockIdx.y * TM;
    const int colBase = blockIdx.x * TN;

    const int rIn = lane >> 2;
    const int cIn = (lane & 3) * 8;

    f32x4 acc[MT][NT];
#pragma unroll
    for (int m = 0; m < MT; ++m)
#pragma unroll
        for (int n = 0; n < NT; ++n)
            acc[m][n] = (f32x4){0.f, 0.f, 0.f, 0.f};

    auto stage = [&](int buf, int k0) {
#pragma unroll
        for (int p = 0; p < NCHUNK / 4; ++p) {
            const int c = wid + p * 4;
            if (c < CA) {
                const int r = c * 16 + rIn;
                async16(&A[(size_t)(rowBase + r) * K + k0 + cIn], &As[buf][c * 512]);
            } else {
                const int r = (c - CA) * 16 + rIn;
                async16(&Bt[(size_t)(colBase + r) * K + k0 + cIn], &Bs[buf][(c - CA) * 512]);
            }
        }
    };

    const int nk = K >> 5;
    stage(0, 0);

    for (int i = 0; i < nk; ++i) {
        __syncthreads();
        if (i + 1 < nk) stage((i + 1) & 1, (i + 1) << 5);

        const int b = i & 1;
        half8 af[MT], bf[NT];
#pragma unroll
        for (int m = 0; m < MT; ++m)
            af[m] = *(const half8*)(&As[b][(wrow * WM + m * 16 + l15) * 32 + quad * 8]);
#pragma unroll
        for (int n = 0; n < NT; ++n)
            bf[n] = *(const half8*)(&Bs[b][(wcol * WN + n * 16 + l15) * 32 + quad * 8]);

#pragma unroll
        for (int m = 0; m < MT; ++m)
#pragma unroll
            for (int n = 0; n < NT; ++n)
                acc[m][n] = __builtin_amdgcn_mfma_f32_16x16x32_f16(
                    af[m], bf[n], acc[m][n], 0, 0, 0);
    }

#pragma unroll
    for (int m = 0; m < MT; ++m) {
#pragma unroll
        for (int n = 0; n < NT; ++n) {
            int col = colBase + wcol * WN + n * 16 + l15;
#pragma unroll
            for (int r = 0; r < 4; ++r) {
                int row = rowBase + wrow * WM + m * 16 + quad * 4 + r;
                C[(size_t)row * Nc + col] = (_Float16)acc[m][n][r];
            }
        }
    }
}

// ---------------------------------------------------------------------------
// SpMM, XCD-adaptive feature-sliced. Slice = 128 feats (2.5 MB of S per
// slice -> fits one XCD's 4 MB L2). Each block picks slice = xcc_id & (NS-1),
// waves grab 8-row chunks from a per-slice atomic counter. Wave 0 of each
// block drains remaining slices afterwards (correctness never depends on
// xcc value). Wave: 4 edge-groups x 16 lanes x 8 feats; butterfly reduce.
// ---------------------------------------------------------------------------
template <int D, bool FINAL>
__global__ __launch_bounds__(256) void spmm_xcd(
    const int* __restrict__ row_ptr,
    const float2* __restrict__ ev,
    const _Float16* __restrict__ S,     // [M_PAD x D]
    const float* __restrict__ bias,     // [D]
    _Float16* __restrict__ Hout,        // [M_PAD x 2D] if !FINAL
    float* __restrict__ Fout,           // [N_NODES x D] if FINAL
    int* __restrict__ work)             // NS counters, pre-zeroed
{
    constexpr int NS = D / 128;
    const int lane = threadIdx.x & 63;
    const int wid  = threadIdx.x >> 6;
    const int g = lane >> 4;            // edge-group 0..3
    const int l = lane & 15;            // feature-lane

    const int s0 = (int)(xcc_id() & (NS - 1));

    auto process = [&](int sl) {
        const _Float16* __restrict__ Sb = S + sl * 128 + l * 8;
        const int f0 = sl * 128 + l * 8;
        const f32x4 b0 = *(const f32x4*)(bias + f0);
        const f32x4 b1 = *(const f32x4*)(bias + f0 + 4);
        for (;;) {
            int base;
            if (lane == 0) base = atomicAdd(&work[sl], 8);
            base = __shfl(base, 0, 64);
            if (base >= N_NODES) break;
            const int rend = min(base + 8, N_NODES);
            for (int row = base; row < rend; ++row) {
                const int r0 = row_ptr[row];
                const int r1 = row_ptr[row + 1];
                float acc[8];
#pragma unroll
                for (int j = 0; j < 8; ++j) acc[j] = 0.f;

                int e = r0 + g;
                for (; e + 4 < r1; e += 8) {
                    float2 p0 = ev[e];
                    float2 p1 = ev[e + 4];
                    half8 v0 = *(const half8*)(Sb + (size_t)__float_as_int(p0.x) * D);
                    half8 v1 = *(const half8*)(Sb + (size_t)__float_as_int(p1.x) * D);
#pragma unroll
                    for (int j = 0; j < 8; ++j) {
                        acc[j] += p0.y * (float)v0[j];
                        acc[j] += p1.y * (float)v1[j];
                    }
                }
                if (e < r1) {
                    float2 p0 = ev[e];
                    half8 v0 = *(const half8*)(Sb + (size_t)__float_as_int(p0.x) * D);
#pragma unroll
                    for (int j = 0; j < 8; ++j) acc[j] += p0.y * (float)v0[j];
                }

#pragma unroll
                for (int j = 0; j < 8; ++j) {
                    acc[j] += __shfl_xor(acc[j], 16, 64);
                    acc[j] += __shfl_xor(acc[j], 32, 64);
                }

                if constexpr (FINAL) {
                    if (g == 0) {
                        f32x4 o = {acc[0] + b0[0], acc[1] + b0[1],
                                   acc[2] + b0[2], acc[3] + b0[3]};
                        *(f32x4*)(Fout + (size_t)row * D + f0) = o;
                    } else if (g == 1) {
                        f32x4 o = {acc[4] + b1[0], acc[5] + b1[1],
                                   acc[6] + b1[2], acc[7] + b1[3]};
                        *(f32x4*)(Fout + (size_t)row * D + f0 + 4) = o;
                    }
                } else {
                    float v[8];
#pragma unroll
                    for (int j = 0; j < 4; ++j) v[j] = acc[j] + b0[j];
#pragma unroll
                    for (int j = 0; j < 4; ++j) v[4 + j] = acc[4 + j] + b1[j];
                    if (g == 0) {                   // relu half
                        half8 h;
#pragma unroll
                        for (int j = 0; j < 8; ++j)
                            h[j] = (_Float16)(v[j] > 0.f ? v[j] : 0.f);
                        *(half8*)(Hout + (size_t)row * (2 * D) + f0) = h;
                    } else if (g == 1) {            // raw half
                        half8 h;
#pragma unroll
                        for (int j = 0; j < 8; ++j) h[j] = (_Float16)v[j];
                        *(half8*)(Hout + (size_t)row * (2 * D) + D + f0) = h;
                    }
                }
            }
        }
    };

    process(s0);
    if (wid == 0) {
        for (int ds = 1; ds < NS; ++ds) process((s0 + ds) & (NS - 1));
    }
}

// ---------------------------------------------------------------------------
static inline char* alignp(char* p, size_t a) {
    return (char*)(((uintptr_t)p + a - 1) & ~(uintptr_t)(a - 1));
}

extern "C" void kernel_launch(void* const* d_in, const int* in_sizes, int n_in,
                              void* d_out, int out_size, void* d_ws, size_t ws_size,
                              hipStream_t stream) {
    const float* x        = (const float*)d_in[0];   // [10000 x 512]
    const int*   edge_row = (const int*)d_in[1];     // [E]
    const int*   edge_col = (const int*)d_in[2];     // [E]
    const float* edge_val = (const float*)d_in[3];   // [E]
    const float* W0 = (const float*)d_in[4];         // [512 x 512]
    const float* W1 = (const float*)d_in[5];         // [1024 x 512]
    const float* W2 = (const float*)d_in[6];         // [1024 x 256]
    const float* b0 = (const float*)d_in[7];
    const float* b1 = (const float*)d_in[8];
    const float* b2 = (const float*)d_in[9];
    float* out = (float*)d_out;                      // [10000 x 256]

    const int E = N_EDGES;

    // ---- workspace carve-up ----
    char* p = (char*)d_ws;
    _Float16* Xh  = (_Float16*)alignp(p, 256);  p = (char*)(Xh  + (size_t)M_PAD * 512);
    _Float16* S   = (_Float16*)alignp(p, 256);  p = (char*)(S   + (size_t)M_PAD * 512);
    _Float16* H   = (_Float16*)alignp(p, 256);  p = (char*)(H   + (size_t)M_PAD * 1024);
    _Float16* W0t = (_Float16*)alignp(p, 256);  p = (char*)(W0t + (size_t)512 * 512);
    _Float16* W1t = (_Float16*)alignp(p, 256);  p = (char*)(W1t + (size_t)512 * 1024);
    _Float16* W2t = (_Float16*)alignp(p, 256);  p = (char*)(W2t + (size_t)256 * 1024);
    int*    counts  = (int*)alignp(p, 256);     p = (char*)(counts  + N_NODES);
    int*    row_ptr = (int*)alignp(p, 256);     p = (char*)(row_ptr + N_NODES + 1);
    int*    cursor  = (int*)alignp(p, 256);     p = (char*)(cursor  + N_NODES);
    int*    work    = (int*)alignp(p, 256);     p = (char*)(work    + 16);
    float2* ev      = (float2*)alignp(p, 256);  p = (char*)(ev      + E);

    // ---- prep (conv + tiled transposes + zero), then CSR build ----
    prep<<<PREP_BLKS, 256, 0, stream>>>(x, Xh, W0, W0t, W1, W1t, W2, W2t,
                                        counts, work);
    hist_rows<<<(E + 255) / 256, 256, 0, stream>>>(edge_row, counts, E);
    scan_rowptr<<<1, 1024, 0, stream>>>(counts, row_ptr, cursor);
    scatter_edges<<<(E + 255) / 256, 256, 0, stream>>>(edge_row, edge_col, edge_val,
                                                       cursor, ev, E);

    // ---- layer 0 ----
    gemm_f16_t<64, 128><<<dim3(4, M_PAD / 64), 256, 0, stream>>>(Xh, W0t, S, 512, 512);
    spmm_xcd<512, false><<<1024, 256, 0, stream>>>(row_ptr, ev, S, b0, H, nullptr, work);
    // ---- layer 1 ----
    gemm_f16_t<64, 128><<<dim3(4, M_PAD / 64), 256, 0, stream>>>(H, W1t, S, 1024, 512);
    spmm_xcd<512, false><<<1024, 256, 0, stream>>>(row_ptr, ev, S, b1, H, nullptr, work + 4);
    // ---- layer 2 ----
    gemm_f16_t<64, 64><<<dim3(4, M_PAD / 64), 256, 0, stream>>>(H, W2t, S, 1024, 256);
    spmm_xcd<256, true><<<1024, 256, 0, stream>>>(row_ptr, ev, S, b2, nullptr, out, work + 8);
}

// Round 7
// 272.372 us; speedup vs baseline: 2.3190x; 2.3190x over previous
//
#include <hip/hip_runtime.h>
#include <hip/hip_bf16.h>
#include <stdint.h>
#include <type_traits>

// ---------------------------------------------------------------------------
// GCN on MI355X: 3x (dense GEMM -> spmm -> bias [-> relu -> concat])
// fp16 activations/weights, fp32 accumulation everywhere.
// R7: revert to R5's measured-best spmm (1 row-slice per wave, 10000-block
//     grid, slice = blockIdx & (NS-1), no atomics) with gather unroll x4;
//     keep R6's parallel scan + LDS-tiled transposes. GEMM unchanged (R5).
// ---------------------------------------------------------------------------

typedef _Float16 half8 __attribute__((ext_vector_type(8)));
typedef _Float16 half4 __attribute__((ext_vector_type(4)));
typedef float    f32x4 __attribute__((ext_vector_type(4)));

#define N_NODES 10000
#define M_PAD   10112   // 158 * 64
#define N_EDGES 320000

__device__ __forceinline__ void async16(const void* g, void* l) {
    __builtin_amdgcn_global_load_lds(
        (const __attribute__((address_space(1))) void*)g,
        (__attribute__((address_space(3))) void*)l, 16, 0, 0);
}

// ---------------------------------------------------------------------------
// prep (block-segmented): x fp32->fp16 (5000 blks), LDS-tiled W transposes
// (256+512+256 blks), zero counts (40 blks).
// ---------------------------------------------------------------------------
#define PREP_XB   5000
#define PREP_W0B  256    // 512x512  : 16x16 tiles of 32x32
#define PREP_W1B  512    // 1024x512 : 32x16
#define PREP_W2B  256    // 1024x256 : 32x8
#define PREP_ZB   40
#define PREP_BLKS (PREP_XB + PREP_W0B + PREP_W1B + PREP_W2B + PREP_ZB)

__device__ __forceinline__ void tile_tr(const float* __restrict__ W,
                                        _Float16* __restrict__ Wt,
                                        int K, int Nc, int tR, int tC, int t) {
    __shared__ float tile[32][33];
    const int ty = t >> 5, tx = t & 31;
#pragma unroll
    for (int it = 0; it < 4; ++it)
        tile[ty + 8 * it][tx] = W[(size_t)(tR * 32 + ty + 8 * it) * Nc + tC * 32 + tx];
    __syncthreads();
#pragma unroll
    for (int it = 0; it < 4; ++it)
        Wt[(size_t)(tC * 32 + ty + 8 * it) * K + tR * 32 + tx] =
            (_Float16)tile[tx][ty + 8 * it];
}

__global__ __launch_bounds__(256) void prep(
    const float* __restrict__ x,  _Float16* __restrict__ Xh,
    const float* __restrict__ W0, _Float16* __restrict__ W0t,
    const float* __restrict__ W1, _Float16* __restrict__ W1t,
    const float* __restrict__ W2, _Float16* __restrict__ W2t,
    int* __restrict__ counts) {
    const int t = threadIdx.x;
    int b = blockIdx.x;
    if (b < PREP_XB) {
        int i = b * 256 + t;                 // exactly 10000*512/4 threads
        f32x4 v = *(const f32x4*)(x + (size_t)i * 4);
        half4 h;
        h[0] = (_Float16)v[0]; h[1] = (_Float16)v[1];
        h[2] = (_Float16)v[2]; h[3] = (_Float16)v[3];
        *(half4*)(Xh + (size_t)i * 4) = h;
        return;
    }
    b -= PREP_XB;
    if (b < PREP_W0B) { tile_tr(W0, W0t, 512, 512, b >> 4, b & 15, t); return; }
    b -= PREP_W0B;
    if (b < PREP_W1B) { tile_tr(W1, W1t, 1024, 512, b >> 4, b & 15, t); return; }
    b -= PREP_W1B;
    if (b < PREP_W2B) { tile_tr(W2, W2t, 1024, 256, b >> 3, b & 7, t); return; }
    b -= PREP_W2B;
    {
        int i = b * 256 + t;
        if (i < N_NODES) counts[i] = 0;
    }
}

// ---------------------------------------------------------------------------
// CSR build
// ---------------------------------------------------------------------------
__global__ void hist_rows(const int* __restrict__ rows, int* __restrict__ counts, int E) {
    int i = blockIdx.x * blockDim.x + threadIdx.x;
    if (i < E) atomicAdd(&counts[rows[i]], 1);
}

// one block, 1024 threads: exclusive scan of counts -> row_ptr, cursor
__global__ __launch_bounds__(1024) void scan_rowptr(
    const int* __restrict__ counts,
    int* __restrict__ row_ptr,
    int* __restrict__ cursor) {
    const int t = threadIdx.x, lane = t & 63, wid = t >> 6;
    const int base = t * 10;
    int c[10];
    int s = 0;
    if (base < N_NODES) {
#pragma unroll
        for (int j = 0; j < 10; ++j) { s += counts[base + j]; c[j] = s; }  // inclusive
    }
    int v = s;
#pragma unroll
    for (int d = 1; d < 64; d <<= 1) {
        int u = __shfl_up(v, d, 64);
        if (lane >= d) v += u;
    }
    __shared__ int wsum[16];
    if (lane == 63) wsum[wid] = v;
    __syncthreads();
    if (t == 0) {
        int run = 0;
#pragma unroll
        for (int i = 0; i < 16; ++i) { int x = wsum[i]; wsum[i] = run; run += x; }
    }
    __syncthreads();
    if (base < N_NODES) {
        const int excl = wsum[wid] + v - s;
        row_ptr[base] = excl; cursor[base] = excl;
#pragma unroll
        for (int j = 1; j < 10; ++j) {
            int val = excl + c[j - 1];
            row_ptr[base + j] = val; cursor[base + j] = val;
        }
    }
    if (t == 0) row_ptr[N_NODES] = N_EDGES;
}

// packed edge record: {col as int bits, val}
__global__ void scatter_edges(const int* __restrict__ rows,
                              const int* __restrict__ cols,
                              const float* __restrict__ vals,
                              int* __restrict__ cursor,
                              float2* __restrict__ ev, int E) {
    int i = blockIdx.x * blockDim.x + threadIdx.x;
    if (i < E) {
        int r = rows[i];
        int p = atomicAdd(&cursor[r], 1);
        ev[p] = make_float2(__int_as_float(cols[i]), vals[i]);
    }
}

// ---------------------------------------------------------------------------
// GEMM: C[M_PAD x Nc] = A[M_PAD x K] * Bt[Nc x K]^T. fp16 in/out, fp32 acc.
// Tile TM x TN, BK=32, 4 waves in 2x2, double-buffered LDS, global_load_lds
// width=16 staging. TM=64 -> 632 blocks (2.5/CU).
// ---------------------------------------------------------------------------
template <int TM, int TN>
__global__ __launch_bounds__(256) void gemm_f16_t(
    const _Float16* __restrict__ A,
    const _Float16* __restrict__ Bt,
    _Float16* __restrict__ C,
    int K, int Nc)
{
    constexpr int WM = TM / 2;
    constexpr int WN = TN / 2;
    constexpr int MT = WM / 16;
    constexpr int NT = WN / 16;
    constexpr int NCHUNK = (TM + TN) / 16;
    constexpr int CA = TM / 16;

    __shared__ _Float16 As[2][TM * 32];
    __shared__ _Float16 Bs[2][TN * 32];

    const int t    = threadIdx.x;
    const int lane = t & 63;
    const int wid  = t >> 6;
    const int wrow = wid >> 1;
    const int wcol = wid & 1;
    const int quad = lane >> 4;
    const int l15  = lane & 15;

    const int rowBase = blockIdx.y * TM;
    const int colBase = blockIdx.x * TN;

    const int rIn = lane >> 2;
    const int cIn = (lane & 3) * 8;

    f32x4 acc[MT][NT];
#pragma unroll
    for (int m = 0; m < MT; ++m)
#pragma unroll
        for (int n = 0; n < NT; ++n)
            acc[m][n] = (f32x4){0.f, 0.f, 0.f, 0.f};

    auto stage = [&](int buf, int k0) {
#pragma unroll
        for (int p = 0; p < NCHUNK / 4; ++p) {
            const int c = wid + p * 4;
            if (c < CA) {
                const int r = c * 16 + rIn;
                async16(&A[(size_t)(rowBase + r) * K + k0 + cIn], &As[buf][c * 512]);
            } else {
                const int r = (c - CA) * 16 + rIn;
                async16(&Bt[(size_t)(colBase + r) * K + k0 + cIn], &Bs[buf][(c - CA) * 512]);
            }
        }
    };

    const int nk = K >> 5;
    stage(0, 0);

    for (int i = 0; i < nk; ++i) {
        __syncthreads();
        if (i + 1 < nk) stage((i + 1) & 1, (i + 1) << 5);

        const int b = i & 1;
        half8 af[MT], bf[NT];
#pragma unroll
        for (int m = 0; m < MT; ++m)
            af[m] = *(const half8*)(&As[b][(wrow * WM + m * 16 + l15) * 32 + quad * 8]);
#pragma unroll
        for (int n = 0; n < NT; ++n)
            bf[n] = *(const half8*)(&Bs[b][(wcol * WN + n * 16 + l15) * 32 + quad * 8]);

#pragma unroll
        for (int m = 0; m < MT; ++m)
#pragma unroll
            for (int n = 0; n < NT; ++n)
                acc[m][n] = __builtin_amdgcn_mfma_f32_16x16x32_f16(
                    af[m], bf[n], acc[m][n], 0, 0, 0);
    }

#pragma unroll
    for (int m = 0; m < MT; ++m) {
#pragma unroll
        for (int n = 0; n < NT; ++n) {
            int col = colBase + wcol * WN + n * 16 + l15;
#pragma unroll
            for (int r = 0; r < 4; ++r) {
                int row = rowBase + wrow * WM + m * 16 + quad * 4 + r;
                C[(size_t)row * Nc + col] = (_Float16)acc[m][n][r];
            }
        }
    }
}

// ---------------------------------------------------------------------------
// SpMM, feature-sliced (R5 structure, unroll x4): slice = 128 features.
// Block = 4 waves = 4 rows of one slice; slice s = blockIdx & (NS-1) so the
// dispatch round-robin spreads slices across XCDs (perf heuristic only).
// Wave: 4 edge-groups x 16 lanes; lane gathers 16B (8 feats) of S[col,slice],
// 4 independent gathers in flight; butterfly shfl_xor(16,32) reduce; fused
// bias(+relu+concat) or fp32 final store.
// ---------------------------------------------------------------------------
template <int D, bool FINAL>
__global__ __launch_bounds__(256) void spmm_slice(
    const int* __restrict__ row_ptr,
    const float2* __restrict__ ev,
    const _Float16* __restrict__ S,     // [M_PAD x D]
    const float* __restrict__ bias,     // [D]
    _Float16* __restrict__ Hout,        // [M_PAD x 2D] if !FINAL
    float* __restrict__ Fout)           // [N_NODES x D] if FINAL
{
    constexpr int NS = D / 128;         // slices
    const int s  = blockIdx.x & (NS - 1);
    const int rq = blockIdx.x / NS;
    const int w  = threadIdx.x >> 6;    // wave -> row within quad
    const int row = rq * 4 + w;
    const int lane = threadIdx.x & 63;
    const int g = lane >> 4;            // edge-group 0..3
    const int l = lane & 15;            // feature-lane

    const int r0 = row_ptr[row];
    const int r1 = row_ptr[row + 1];

    float acc[8];
#pragma unroll
    for (int j = 0; j < 8; ++j) acc[j] = 0.f;

    const _Float16* __restrict__ Sb = S + s * 128 + l * 8;

    int e = r0 + g;
    // unroll 4: per-group stride 4 -> quad stride 16; 4 gathers in flight
    for (; e + 12 < r1; e += 16) {
        float2 p[4];
        half8  v[4];
#pragma unroll
        for (int u = 0; u < 4; ++u) p[u] = ev[e + 4 * u];
#pragma unroll
        for (int u = 0; u < 4; ++u)
            v[u] = *(const half8*)(Sb + (size_t)__float_as_int(p[u].x) * D);
#pragma unroll
        for (int u = 0; u < 4; ++u)
#pragma unroll
            for (int j = 0; j < 8; ++j) acc[j] += p[u].y * (float)v[u][j];
    }
    for (; e + 4 < r1; e += 8) {
        float2 p0 = ev[e];
        float2 p1 = ev[e + 4];
        half8 v0 = *(const half8*)(Sb + (size_t)__float_as_int(p0.x) * D);
        half8 v1 = *(const half8*)(Sb + (size_t)__float_as_int(p1.x) * D);
#pragma unroll
        for (int j = 0; j < 8; ++j) {
            acc[j] += p0.y * (float)v0[j];
            acc[j] += p1.y * (float)v1[j];
        }
    }
    if (e < r1) {
        float2 p0 = ev[e];
        half8 v0 = *(const half8*)(Sb + (size_t)__float_as_int(p0.x) * D);
#pragma unroll
        for (int j = 0; j < 8; ++j) acc[j] += p0.y * (float)v0[j];
    }

    // butterfly across the 4 edge-groups (lanes xor 16, xor 32)
#pragma unroll
    for (int j = 0; j < 8; ++j) {
        acc[j] += __shfl_xor(acc[j], 16, 64);
        acc[j] += __shfl_xor(acc[j], 32, 64);
    }

    const int f0 = s * 128 + l * 8;
    f32x4 b0 = *(const f32x4*)(bias + f0);
    f32x4 b1 = *(const f32x4*)(bias + f0 + 4);

    if constexpr (FINAL) {
        if (g == 0) {
            f32x4 o = {acc[0] + b0[0], acc[1] + b0[1], acc[2] + b0[2], acc[3] + b0[3]};
            *(f32x4*)(Fout + (size_t)row * D + f0) = o;
        } else if (g == 1) {
            f32x4 o = {acc[4] + b1[0], acc[5] + b1[1], acc[6] + b1[2], acc[7] + b1[3]};
            *(f32x4*)(Fout + (size_t)row * D + f0 + 4) = o;
        }
    } else {
        float v[8];
#pragma unroll
        for (int j = 0; j < 4; ++j) v[j] = acc[j] + b0[j];
#pragma unroll
        for (int j = 0; j < 4; ++j) v[4 + j] = acc[4 + j] + b1[j];
        if (g == 0) {                   // relu half
            half8 h;
#pragma unroll
            for (int j = 0; j < 8; ++j) h[j] = (_Float16)(v[j] > 0.f ? v[j] : 0.f);
            *(half8*)(Hout + (size_t)row * (2 * D) + f0) = h;
        } else if (g == 1) {            // raw half
            half8 h;
#pragma unroll
            for (int j = 0; j < 8; ++j) h[j] = (_Float16)v[j];
            *(half8*)(Hout + (size_t)row * (2 * D) + D + f0) = h;
        }
    }
}

// ---------------------------------------------------------------------------
static inline char* alignp(char* p, size_t a) {
    return (char*)(((uintptr_t)p + a - 1) & ~(uintptr_t)(a - 1));
}

extern "C" void kernel_launch(void* const* d_in, const int* in_sizes, int n_in,
                              void* d_out, int out_size, void* d_ws, size_t ws_size,
                              hipStream_t stream) {
    const float* x        = (const float*)d_in[0];   // [10000 x 512]
    const int*   edge_row = (const int*)d_in[1];     // [E]
    const int*   edge_col = (const int*)d_in[2];     // [E]
    const float* edge_val = (const float*)d_in[3];   // [E]
    const float* W0 = (const float*)d_in[4];         // [512 x 512]
    const float* W1 = (const float*)d_in[5];         // [1024 x 512]
    const float* W2 = (const float*)d_in[6];         // [1024 x 256]
    const float* b0 = (const float*)d_in[7];
    const float* b1 = (const float*)d_in[8];
    const float* b2 = (const float*)d_in[9];
    float* out = (float*)d_out;                      // [10000 x 256]

    const int E = N_EDGES;

    // ---- workspace carve-up ----
    char* p = (char*)d_ws;
    _Float16* Xh  = (_Float16*)alignp(p, 256);  p = (char*)(Xh  + (size_t)M_PAD * 512);
    _Float16* S   = (_Float16*)alignp(p, 256);  p = (char*)(S   + (size_t)M_PAD * 512);
    _Float16* H   = (_Float16*)alignp(p, 256);  p = (char*)(H   + (size_t)M_PAD * 1024);
    _Float16* W0t = (_Float16*)alignp(p, 256);  p = (char*)(W0t + (size_t)512 * 512);
    _Float16* W1t = (_Float16*)alignp(p, 256);  p = (char*)(W1t + (size_t)512 * 1024);
    _Float16* W2t = (_Float16*)alignp(p, 256);  p = (char*)(W2t + (size_t)256 * 1024);
    int*    counts  = (int*)alignp(p, 256);     p = (char*)(counts  + N_NODES);
    int*    row_ptr = (int*)alignp(p, 256);     p = (char*)(row_ptr + N_NODES + 1);
    int*    cursor  = (int*)alignp(p, 256);     p = (char*)(cursor  + N_NODES);
    float2* ev      = (float2*)alignp(p, 256);  p = (char*)(ev      + E);

    // ---- prep (conv + tiled transposes + zero), then CSR build ----
    prep<<<PREP_BLKS, 256, 0, stream>>>(x, Xh, W0, W0t, W1, W1t, W2, W2t, counts);
    hist_rows<<<(E + 255) / 256, 256, 0, stream>>>(edge_row, counts, E);
    scan_rowptr<<<1, 1024, 0, stream>>>(counts, row_ptr, cursor);
    scatter_edges<<<(E + 255) / 256, 256, 0, stream>>>(edge_row, edge_col, edge_val,
                                                       cursor, ev, E);

    // ---- layer 0 ----
    gemm_f16_t<64, 128><<<dim3(4, M_PAD / 64), 256, 0, stream>>>(Xh, W0t, S, 512, 512);
    spmm_slice<512, false><<<(N_NODES / 4) * 4, 256, 0, stream>>>(row_ptr, ev, S, b0, H, nullptr);
    // ---- layer 1 ----
    gemm_f16_t<64, 128><<<dim3(4, M_PAD / 64), 256, 0, stream>>>(H, W1t, S, 1024, 512);
    spmm_slice<512, false><<<(N_NODES / 4) * 4, 256, 0, stream>>>(row_ptr, ev, S, b1, H, nullptr);
    // ---- layer 2 ----
    gemm_f16_t<64, 64><<<dim3(4, M_PAD / 64), 256, 0, stream>>>(H, W2t, S, 1024, 256);
    spmm_slice<256, true><<<(N_NODES / 4) * 2, 256, 0, stream>>>(row_ptr, ev, S, b2, nullptr, out);
}

// Round 8
// 263.978 us; speedup vs baseline: 2.3927x; 1.0318x over previous
//
#include <hip/hip_runtime.h>
#include <hip/hip_bf16.h>
#include <stdint.h>
#include <type_traits>

// ---------------------------------------------------------------------------
// GCN on MI355X: 3x (dense GEMM -> spmm -> bias [-> relu -> concat])
// fp16 activations/weights, fp32 accumulation everywhere.
// R8: dispatch fusion of independent stages. counts-zero -> hipMemsetAsync;
//     prep+hist fused; scatter+GEMM0 fused (scatter hides under MFMA).
//     Inner loops identical to R7 (measured best).
// ---------------------------------------------------------------------------

typedef _Float16 half8 __attribute__((ext_vector_type(8)));
typedef _Float16 half4 __attribute__((ext_vector_type(4)));
typedef float    f32x4 __attribute__((ext_vector_type(4)));

#define N_NODES 10000
#define M_PAD   10112   // 158 * 64
#define N_EDGES 320000

__device__ __forceinline__ void async16(const void* g, void* l) {
    __builtin_amdgcn_global_load_lds(
        (const __attribute__((address_space(1))) void*)g,
        (__attribute__((address_space(3))) void*)l, 16, 0, 0);
}

// ---------------------------------------------------------------------------
// GEMM body: C[M_PAD x Nc] = A[M_PAD x K] * Bt[Nc x K]^T. fp16 in/out,
// fp32 acc. Tile TM x TN, BK=32, 4 waves 2x2, double-buffered LDS,
// global_load_lds width=16 staging. (R5/R7-proven.)
// ---------------------------------------------------------------------------
template <int TM, int TN>
__device__ __forceinline__ void gemm_body(
    int bx, int by,
    const _Float16* __restrict__ A,
    const _Float16* __restrict__ Bt,
    _Float16* __restrict__ C,
    int K, int Nc)
{
    constexpr int WM = TM / 2;
    constexpr int WN = TN / 2;
    constexpr int MT = WM / 16;
    constexpr int NT = WN / 16;
    constexpr int NCHUNK = (TM + TN) / 16;
    constexpr int CA = TM / 16;

    __shared__ _Float16 As[2][TM * 32];
    __shared__ _Float16 Bs[2][TN * 32];

    const int t    = threadIdx.x;
    const int lane = t & 63;
    const int wid  = t >> 6;
    const int wrow = wid >> 1;
    const int wcol = wid & 1;
    const int quad = lane >> 4;
    const int l15  = lane & 15;

    const int rowBase = by * TM;
    const int colBase = bx * TN;

    const int rIn = lane >> 2;
    const int cIn = (lane & 3) * 8;

    f32x4 acc[MT][NT];
#pragma unroll
    for (int m = 0; m < MT; ++m)
#pragma unroll
        for (int n = 0; n < NT; ++n)
            acc[m][n] = (f32x4){0.f, 0.f, 0.f, 0.f};

    auto stage = [&](int buf, int k0) {
#pragma unroll
        for (int p = 0; p < NCHUNK / 4; ++p) {
            const int c = wid + p * 4;
            if (c < CA) {
                const int r = c * 16 + rIn;
                async16(&A[(size_t)(rowBase + r) * K + k0 + cIn], &As[buf][c * 512]);
            } else {
                const int r = (c - CA) * 16 + rIn;
                async16(&Bt[(size_t)(colBase + r) * K + k0 + cIn], &Bs[buf][(c - CA) * 512]);
            }
        }
    };

    const int nk = K >> 5;
    stage(0, 0);

    for (int i = 0; i < nk; ++i) {
        __syncthreads();
        if (i + 1 < nk) stage((i + 1) & 1, (i + 1) << 5);

        const int b = i & 1;
        half8 af[MT], bf[NT];
#pragma unroll
        for (int m = 0; m < MT; ++m)
            af[m] = *(const half8*)(&As[b][(wrow * WM + m * 16 + l15) * 32 + quad * 8]);
#pragma unroll
        for (int n = 0; n < NT; ++n)
            bf[n] = *(const half8*)(&Bs[b][(wcol * WN + n * 16 + l15) * 32 + quad * 8]);

#pragma unroll
        for (int m = 0; m < MT; ++m)
#pragma unroll
            for (int n = 0; n < NT; ++n)
                acc[m][n] = __builtin_amdgcn_mfma_f32_16x16x32_f16(
                    af[m], bf[n], acc[m][n], 0, 0, 0);
    }

#pragma unroll
    for (int m = 0; m < MT; ++m) {
#pragma unroll
        for (int n = 0; n < NT; ++n) {
            int col = colBase + wcol * WN + n * 16 + l15;
#pragma unroll
            for (int r = 0; r < 4; ++r) {
                int row = rowBase + wrow * WM + m * 16 + quad * 4 + r;
                C[(size_t)row * Nc + col] = (_Float16)acc[m][n][r];
            }
        }
    }
}

template <int TM, int TN>
__global__ __launch_bounds__(256) void gemm_f16_t(
    const _Float16* __restrict__ A,
    const _Float16* __restrict__ Bt,
    _Float16* __restrict__ C,
    int K, int Nc)
{
    gemm_body<TM, TN>(blockIdx.x, blockIdx.y, A, Bt, C, K, Nc);
}

// ---------------------------------------------------------------------------
// prep+hist fused (block-segmented): x fp32->fp16 (5000 blks), LDS-tiled W
// transposes (256+512+256 blks), edge-row histogram (1250 blks; counts
// pre-zeroed by a hipMemsetAsync node).
// ---------------------------------------------------------------------------
#define PREP_XB   5000
#define PREP_W0B  256    // 512x512  : 16x16 tiles of 32x32
#define PREP_W1B  512    // 1024x512 : 32x16
#define PREP_W2B  256    // 1024x256 : 32x8
#define HIST_B    1250   // 320000 / 256
#define PREPH_BLKS (PREP_XB + PREP_W0B + PREP_W1B + PREP_W2B + HIST_B)

__device__ __forceinline__ void tile_tr(const float* __restrict__ W,
                                        _Float16* __restrict__ Wt,
                                        int K, int Nc, int tR, int tC, int t) {
    __shared__ float tile[32][33];
    const int ty = t >> 5, tx = t & 31;
#pragma unroll
    for (int it = 0; it < 4; ++it)
        tile[ty + 8 * it][tx] = W[(size_t)(tR * 32 + ty + 8 * it) * Nc + tC * 32 + tx];
    __syncthreads();
#pragma unroll
    for (int it = 0; it < 4; ++it)
        Wt[(size_t)(tC * 32 + ty + 8 * it) * K + tR * 32 + tx] =
            (_Float16)tile[tx][ty + 8 * it];
}

__global__ __launch_bounds__(256) void prep_hist(
    const float* __restrict__ x,  _Float16* __restrict__ Xh,
    const float* __restrict__ W0, _Float16* __restrict__ W0t,
    const float* __restrict__ W1, _Float16* __restrict__ W1t,
    const float* __restrict__ W2, _Float16* __restrict__ W2t,
    const int* __restrict__ edge_row, int* __restrict__ counts) {
    const int t = threadIdx.x;
    int b = blockIdx.x;
    if (b < PREP_XB) {
        int i = b * 256 + t;                 // exactly 10000*512/4 threads
        f32x4 v = *(const f32x4*)(x + (size_t)i * 4);
        half4 h;
        h[0] = (_Float16)v[0]; h[1] = (_Float16)v[1];
        h[2] = (_Float16)v[2]; h[3] = (_Float16)v[3];
        *(half4*)(Xh + (size_t)i * 4) = h;
        return;
    }
    b -= PREP_XB;
    if (b < PREP_W0B) { tile_tr(W0, W0t, 512, 512, b >> 4, b & 15, t); return; }
    b -= PREP_W0B;
    if (b < PREP_W1B) { tile_tr(W1, W1t, 1024, 512, b >> 4, b & 15, t); return; }
    b -= PREP_W1B;
    if (b < PREP_W2B) { tile_tr(W2, W2t, 1024, 256, b >> 3, b & 7, t); return; }
    b -= PREP_W2B;
    {
        int i = b * 256 + t;
        if (i < N_EDGES) atomicAdd(&counts[edge_row[i]], 1);
    }
}

// ---------------------------------------------------------------------------
// one block, 1024 threads: exclusive scan of counts -> row_ptr, cursor
// ---------------------------------------------------------------------------
__global__ __launch_bounds__(1024) void scan_rowptr(
    const int* __restrict__ counts,
    int* __restrict__ row_ptr,
    int* __restrict__ cursor) {
    const int t = threadIdx.x, lane = t & 63, wid = t >> 6;
    const int base = t * 10;
    int c[10];
    int s = 0;
    if (base < N_NODES) {
#pragma unroll
        for (int j = 0; j < 10; ++j) { s += counts[base + j]; c[j] = s; }  // inclusive
    }
    int v = s;
#pragma unroll
    for (int d = 1; d < 64; d <<= 1) {
        int u = __shfl_up(v, d, 64);
        if (lane >= d) v += u;
    }
    __shared__ int wsum[16];
    if (lane == 63) wsum[wid] = v;
    __syncthreads();
    if (t == 0) {
        int run = 0;
#pragma unroll
        for (int i = 0; i < 16; ++i) { int x = wsum[i]; wsum[i] = run; run += x; }
    }
    __syncthreads();
    if (base < N_NODES) {
        const int excl = wsum[wid] + v - s;
        row_ptr[base] = excl; cursor[base] = excl;
#pragma unroll
        for (int j = 1; j < 10; ++j) {
            int val = excl + c[j - 1];
            row_ptr[base + j] = val; cursor[base + j] = val;
        }
    }
    if (t == 0) row_ptr[N_NODES] = N_EDGES;
}

// ---------------------------------------------------------------------------
// GEMM0 + scatter fused: blocks 0..631 run layer-0 GEMM (4 x 158 tiles);
// blocks 632.. run the CSR edge scatter (latency-bound random writes hide
// under the GEMM's MFMA work).
// ---------------------------------------------------------------------------
#define G0_BLKS 632            // 4 * 158
#define SCAT_BLKS 1250

__global__ __launch_bounds__(256) void gemm0_scatter(
    const _Float16* __restrict__ Xh,
    const _Float16* __restrict__ W0t,
    _Float16* __restrict__ S,
    const int* __restrict__ rows,
    const int* __restrict__ cols,
    const float* __restrict__ vals,
    int* __restrict__ cursor,
    float2* __restrict__ ev) {
    int b = blockIdx.x;
    if (b < G0_BLKS) {
        gemm_body<64, 128>(b & 3, b >> 2, Xh, W0t, S, 512, 512);
        return;
    }
    b -= G0_BLKS;
    int i = b * 256 + threadIdx.x;
    if (i < N_EDGES) {
        int r = rows[i];
        int p = atomicAdd(&cursor[r], 1);
        ev[p] = make_float2(__int_as_float(cols[i]), vals[i]);
    }
}

// ---------------------------------------------------------------------------
// SpMM, feature-sliced (R7-proven): slice = 128 features. Block = 4 waves =
// 4 rows of one slice; slice s = blockIdx & (NS-1). Wave: 4 edge-groups x
// 16 lanes; lane gathers 16B (8 feats), 4 independent gathers in flight;
// butterfly shfl_xor(16,32) reduce; fused bias(+relu+concat) / fp32 store.
// ---------------------------------------------------------------------------
template <int D, bool FINAL>
__global__ __launch_bounds__(256) void spmm_slice(
    const int* __restrict__ row_ptr,
    const float2* __restrict__ ev,
    const _Float16* __restrict__ S,     // [M_PAD x D]
    const float* __restrict__ bias,     // [D]
    _Float16* __restrict__ Hout,        // [M_PAD x 2D] if !FINAL
    float* __restrict__ Fout)           // [N_NODES x D] if FINAL
{
    constexpr int NS = D / 128;         // slices
    const int s  = blockIdx.x & (NS - 1);
    const int rq = blockIdx.x / NS;
    const int w  = threadIdx.x >> 6;    // wave -> row within quad
    const int row = rq * 4 + w;
    const int lane = threadIdx.x & 63;
    const int g = lane >> 4;            // edge-group 0..3
    const int l = lane & 15;            // feature-lane

    const int r0 = row_ptr[row];
    const int r1 = row_ptr[row + 1];

    float acc[8];
#pragma unroll
    for (int j = 0; j < 8; ++j) acc[j] = 0.f;

    const _Float16* __restrict__ Sb = S + s * 128 + l * 8;

    int e = r0 + g;
    // unroll 4: per-group stride 4 -> quad stride 16; 4 gathers in flight
    for (; e + 12 < r1; e += 16) {
        float2 p[4];
        half8  v[4];
#pragma unroll
        for (int u = 0; u < 4; ++u) p[u] = ev[e + 4 * u];
#pragma unroll
        for (int u = 0; u < 4; ++u)
            v[u] = *(const half8*)(Sb + (size_t)__float_as_int(p[u].x) * D);
#pragma unroll
        for (int u = 0; u < 4; ++u)
#pragma unroll
            for (int j = 0; j < 8; ++j) acc[j] += p[u].y * (float)v[u][j];
    }
    for (; e + 4 < r1; e += 8) {
        float2 p0 = ev[e];
        float2 p1 = ev[e + 4];
        half8 v0 = *(const half8*)(Sb + (size_t)__float_as_int(p0.x) * D);
        half8 v1 = *(const half8*)(Sb + (size_t)__float_as_int(p1.x) * D);
#pragma unroll
        for (int j = 0; j < 8; ++j) {
            acc[j] += p0.y * (float)v0[j];
            acc[j] += p1.y * (float)v1[j];
        }
    }
    if (e < r1) {
        float2 p0 = ev[e];
        half8 v0 = *(const half8*)(Sb + (size_t)__float_as_int(p0.x) * D);
#pragma unroll
        for (int j = 0; j < 8; ++j) acc[j] += p0.y * (float)v0[j];
    }

    // butterfly across the 4 edge-groups (lanes xor 16, xor 32)
#pragma unroll
    for (int j = 0; j < 8; ++j) {
        acc[j] += __shfl_xor(acc[j], 16, 64);
        acc[j] += __shfl_xor(acc[j], 32, 64);
    }

    const int f0 = s * 128 + l * 8;
    f32x4 b0 = *(const f32x4*)(bias + f0);
    f32x4 b1 = *(const f32x4*)(bias + f0 + 4);

    if constexpr (FINAL) {
        if (g == 0) {
            f32x4 o = {acc[0] + b0[0], acc[1] + b0[1], acc[2] + b0[2], acc[3] + b0[3]};
            *(f32x4*)(Fout + (size_t)row * D + f0) = o;
        } else if (g == 1) {
            f32x4 o = {acc[4] + b1[0], acc[5] + b1[1], acc[6] + b1[2], acc[7] + b1[3]};
            *(f32x4*)(Fout + (size_t)row * D + f0 + 4) = o;
        }
    } else {
        float v[8];
#pragma unroll
        for (int j = 0; j < 4; ++j) v[j] = acc[j] + b0[j];
#pragma unroll
        for (int j = 0; j < 4; ++j) v[4 + j] = acc[4 + j] + b1[j];
        if (g == 0) {                   // relu half
            half8 h;
#pragma unroll
            for (int j = 0; j < 8; ++j) h[j] = (_Float16)(v[j] > 0.f ? v[j] : 0.f);
            *(half8*)(Hout + (size_t)row * (2 * D) + f0) = h;
        } else if (g == 1) {            // raw half
            half8 h;
#pragma unroll
            for (int j = 0; j < 8; ++j) h[j] = (_Float16)v[j];
            *(half8*)(Hout + (size_t)row * (2 * D) + D + f0) = h;
        }
    }
}

// ---------------------------------------------------------------------------
static inline char* alignp(char* p, size_t a) {
    return (char*)(((uintptr_t)p + a - 1) & ~(uintptr_t)(a - 1));
}

extern "C" void kernel_launch(void* const* d_in, const int* in_sizes, int n_in,
                              void* d_out, int out_size, void* d_ws, size_t ws_size,
                              hipStream_t stream) {
    const float* x        = (const float*)d_in[0];   // [10000 x 512]
    const int*   edge_row = (const int*)d_in[1];     // [E]
    const int*   edge_col = (const int*)d_in[2];     // [E]
    const float* edge_val = (const float*)d_in[3];   // [E]
    const float* W0 = (const float*)d_in[4];         // [512 x 512]
    const float* W1 = (const float*)d_in[5];         // [1024 x 512]
    const float* W2 = (const float*)d_in[6];         // [1024 x 256]
    const float* b0 = (const float*)d_in[7];
    const float* b1 = (const float*)d_in[8];
    const float* b2 = (const float*)d_in[9];
    float* out = (float*)d_out;                      // [10000 x 256]

    const int E = N_EDGES;

    // ---- workspace carve-up ----
    char* p = (char*)d_ws;
    _Float16* Xh  = (_Float16*)alignp(p, 256);  p = (char*)(Xh  + (size_t)M_PAD * 512);
    _Float16* S   = (_Float16*)alignp(p, 256);  p = (char*)(S   + (size_t)M_PAD * 512);
    _Float16* H   = (_Float16*)alignp(p, 256);  p = (char*)(H   + (size_t)M_PAD * 1024);
    _Float16* W0t = (_Float16*)alignp(p, 256);  p = (char*)(W0t + (size_t)512 * 512);
    _Float16* W1t = (_Float16*)alignp(p, 256);  p = (char*)(W1t + (size_t)512 * 1024);
    _Float16* W2t = (_Float16*)alignp(p, 256);  p = (char*)(W2t + (size_t)256 * 1024);
    int*    counts  = (int*)alignp(p, 256);     p = (char*)(counts  + N_NODES);
    int*    row_ptr = (int*)alignp(p, 256);     p = (char*)(row_ptr + N_NODES + 1);
    int*    cursor  = (int*)alignp(p, 256);     p = (char*)(cursor  + N_NODES);
    float2* ev      = (float2*)alignp(p, 256);  p = (char*)(ev      + E);

    // ---- zero counts (graph memset node), then prep+hist fused ----
    hipMemsetAsync(counts, 0, N_NODES * sizeof(int), stream);
    prep_hist<<<PREPH_BLKS, 256, 0, stream>>>(x, Xh, W0, W0t, W1, W1t, W2, W2t,
                                              edge_row, counts);
    scan_rowptr<<<1, 1024, 0, stream>>>(counts, row_ptr, cursor);

    // ---- layer 0 GEMM + edge scatter (independent, fused grid) ----
    gemm0_scatter<<<G0_BLKS + SCAT_BLKS, 256, 0, stream>>>(
        Xh, W0t, S, edge_row, edge_col, edge_val, cursor, ev);
    spmm_slice<512, false><<<(N_NODES / 4) * 4, 256, 0, stream>>>(row_ptr, ev, S, b0, H, nullptr);
    // ---- layer 1 ----
    gemm_f16_t<64, 128><<<dim3(4, M_PAD / 64), 256, 0, stream>>>(H, W1t, S, 1024, 512);
    spmm_slice<512, false><<<(N_NODES / 4) * 4, 256, 0, stream>>>(row_ptr, ev, S, b1, H, nullptr);
    // ---- layer 2 ----
    gemm_f16_t<64, 64><<<dim3(4, M_PAD / 64), 256, 0, stream>>>(H, W2t, S, 1024, 256);
    spmm_slice<256, true><<<(N_NODES / 4) * 2, 256, 0, stream>>>(row_ptr, ev, S, b2, nullptr, out);
}